// Round 7
// baseline (831.964 us; speedup 1.0000x reference)
//
#include <hip/hip_runtime.h>

typedef unsigned int uint_t;

#define N_NODES 100000
#define N_EDGES 1600000
#define D 64
#define D2 4096   // D*D
#define D3 12288  // 3*D2

#define NPAD 100352u  // N_NODES rounded up

#define BSHIFT 9          // 512 nodes per bucket
#define BNODES 512
#define NBUCK 196         // ceil(100000/512)
#define CHUNK 8192        // edges per partition workgroup (196 workgroups)
#define CAP   16384       // LDS staging slots in bucket_csr (mean fill 8192)

// ---------- workspace layout (4-byte units) ----------
#define OFF_GI1   0u
#define OFF_GI2   (OFF_GI1 + D3)
#define OFF_GH1   (OFF_GI2 + D3)
#define OFF_GH2   (OFF_GH1 + D3)
#define OFF_W1    (OFF_GH2 + D3)          // 49152
#define OFF_W2    (OFF_W1 + D2)           // 53248
#define OFF_DEG   (OFF_W2 + D2)           // 57344   int[NPAD]
#define OFF_NORM  (OFF_DEG + NPAD)        // 157696  float[NPAD]
#define OFF_ROWS  (OFF_NORM + NPAD)       // 258048  int[NPAD] rowstart (node-ordered)
#define OFF_BCNT  (OFF_ROWS + NPAD)       // 358400  int[256]
#define OFF_BBASE (OFF_BCNT + 256u)       // 358656  int[256]
#define OFF_BCUR  (OFF_BBASE + 256u)      // 358912  int[256]
#define OFF_CSR   (OFF_BCUR + 256u)       // 359168  int[N_EDGES]
#define OFF_H     (OFF_CSR + 1600000u)    // 1959168 slot holds: bf16 h' (12.8MB) then int2 pairs (12.8MB)
#define OFF_AGG1  (OFF_H + 6400000u)      // 8359168 float[N*D]
// total 14,759,168 units ~= 56.3 MiB

__device__ __forceinline__ float dot4(float4 a, float4 b, float acc) {
    acc = fmaf(a.x, b.x, acc);
    acc = fmaf(a.y, b.y, acc);
    acc = fmaf(a.z, b.z, acc);
    acc = fmaf(a.w, b.w, acc);
    return acc;
}

// round-to-nearest-even f32 -> bf16 (value range here is sane, no NaN concern)
__device__ __forceinline__ uint_t bfr(float f) {
    uint_t u = __float_as_uint(f);
    u += 0x7FFFu + ((u >> 16) & 1u);
    return u >> 16;
}

// K1: GRU matvecs. R6 post-mortem: every >=88-VGPR variant pinned at 4 waves/SIMD
// -> ~17% occupancy -> 1.6 TB/s, 127us. New shape targets the occupancy cliff:
//  - grid split by MATRIX (blocks [0,1536): w_ih x {x1,x2}; [1536,3072): w_hh x
//    {h1,h2}) so a block stages only 2 x-vectors -> 32KB LDS, not 64 VGPR.
//  - one ROW per WAVE (512-thr blocks, 8 waves): lane owns 16 float4 slots,
//    4 groups of 4 prefetched streaming loads, 2 partials, pure shfl reduce.
//  - VGPR ~40 (<64) + 32KB LDS -> 4 blocks/CU = 32 waves/CU resident.
__global__ __launch_bounds__(512) void gru_matvec(
    const float* __restrict__ w_ih, const float* __restrict__ w_hh,
    const float* __restrict__ x1, const float* __restrict__ x2,
    const float* __restrict__ h1, const float* __restrict__ h2,
    float* __restrict__ gi1, float* __restrict__ gi2,
    float* __restrict__ gh1, float* __restrict__ gh2)
{
    __shared__ float4 sA[1024], sB[1024];   // 32 KB: the 2 x-vectors for this half
    const int tid  = threadIdx.x;
    const int half = (blockIdx.x >= 1536);
    const int blk  = blockIdx.x - (half ? 1536 : 0);

    {
        const float4* va = (const float4*)(half ? h1 : x1);
        const float4* vb = (const float4*)(half ? h2 : x2);
#pragma unroll
        for (int i = 0; i < 2; ++i) {
            const int k = tid + i * 512;
            sA[k] = va[k];
            sB[k] = vb[k];
        }
    }
    __syncthreads();

    const int wave = tid >> 6, lane = tid & 63;
    const int row  = blk * 8 + wave;                 // 0..12287
    const float4* wr = (const float4*)((half ? w_hh : w_ih) + (size_t)row * D2);

    float p0 = 0.f, p1 = 0.f;
#pragma unroll
    for (int g = 0; g < 4; ++g) {
        float4 a[4];
#pragma unroll
        for (int k = 0; k < 4; ++k)                  // 4 streaming loads in flight
            a[k] = wr[lane + (g * 4 + k) * 64];
#pragma unroll
        for (int k = 0; k < 4; ++k) {
            const int idx = lane + (g * 4 + k) * 64;
            p0 = dot4(a[k], sA[idx], p0);
            p1 = dot4(a[k], sB[idx], p1);
        }
    }
    // full-wave shuffle reduction (convergent)
#pragma unroll
    for (int m = 32; m > 0; m >>= 1) {
        p0 += __shfl_down(p0, m, 64);
        p1 += __shfl_down(p1, m, 64);
    }
    if (lane == 0) {
        float* oA = half ? gh1 : gi1;
        float* oB = half ? gh2 : gi2;
        oA[row] = p0;
        oB[row] = p1;
    }
}

// K2: GRU gates -> evolved weights w1,w2 (fp32, 4096 each)
__global__ __launch_bounds__(256) void gru_gates(
    const float* __restrict__ gi1, const float* __restrict__ gh1,
    const float* __restrict__ gi2, const float* __restrict__ gh2,
    const float* __restrict__ b_ih, const float* __restrict__ b_hh,
    const float* __restrict__ hw1, const float* __restrict__ hw2,
    float* __restrict__ w1, float* __restrict__ w2)
{
    const int j = blockIdx.x * 256 + threadIdx.x;   // 0..4095
    const int layer = blockIdx.y;
    const float* gi = layer ? gi2 : gi1;
    const float* gh = layer ? gh2 : gh1;
    const float* hw = layer ? hw2 : hw1;
    float* wo = layer ? w2 : w1;

    float ir = gi[j]          + b_ih[j];
    float hr = gh[j]          + b_hh[j];
    float iz = gi[j + D2]     + b_ih[j + D2];
    float hz = gh[j + D2]     + b_hh[j + D2];
    float in_ = gi[j + 2*D2]  + b_ih[j + 2*D2];
    float hn = gh[j + 2*D2]   + b_hh[j + 2*D2];

    float r = 1.f / (1.f + expf(-(ir + hr)));
    float z = 1.f / (1.f + expf(-(iz + hz)));
    float n = tanhf(in_ + r * hn);
    wo[j] = (1.f - z) * n + z * hw[j];
}

// K3: fused in-degree + bucket histogram (grid-stride, LDS-pre-aggregated)
__global__ __launch_bounds__(256) void deg_hist_kernel(
    const int* __restrict__ dst, int* __restrict__ deg, int* __restrict__ bcnt)
{
    __shared__ int hist[256];
    const int tid = threadIdx.x;
    hist[tid] = 0;
    __syncthreads();
    const int stride = gridDim.x * 256;
    for (int e = blockIdx.x * 256 + tid; e < N_EDGES; e += stride) {
        const int d = dst[e];
        atomicAdd(&deg[d], 1);
        atomicAdd(&hist[d >> BSHIFT], 1);
    }
    __syncthreads();
    if (hist[tid]) atomicAdd(&bcnt[tid], hist[tid]);
}

// K4: exclusive scan of 256 bucket counts -> bucket base + write cursor
__global__ __launch_bounds__(256) void bucket_scan_kernel(
    const int* __restrict__ bcnt, int* __restrict__ bbase, int* __restrict__ bcur)
{
    __shared__ int tmp[256];
    const int tid = threadIdx.x;
    const int c = bcnt[tid];
    tmp[tid] = c;
    __syncthreads();
    for (int off = 1; off < 256; off <<= 1) {
        int a = tmp[tid];
        int b = (tid >= off) ? tmp[tid - off] : 0;
        __syncthreads();
        tmp[tid] = a + b;
        __syncthreads();
    }
    const int ex = tmp[tid] - c;
    bbase[tid] = ex;
    bcur[tid]  = ex;
}

// K5: norm = clip(deg,1)^-0.5
__global__ __launch_bounds__(256) void norm_kernel(
    const int* __restrict__ deg, float* __restrict__ norm)
{
    const int n = blockIdx.x * 256 + threadIdx.x;
    if (n < N_NODES) norm[n] = 1.0f / sqrtf(fmaxf((float)deg[n], 1.0f));
}

// K6: partition edges into dst-buckets. All global writes are coalesced runs.
__global__ __launch_bounds__(256) void partition_kernel(
    const int* __restrict__ src, const int* __restrict__ dst,
    int* __restrict__ bcur, int2* __restrict__ pairs)
{
    __shared__ int hist[256];
    __shared__ int lbase[256];
    __shared__ int gbase[256];
    __shared__ int lcur[256];
    __shared__ int2 stage[CHUNK];
    const int tid = threadIdx.x;
    const int e0  = blockIdx.x * CHUNK;
    const int cnt = min(CHUNK, N_EDGES - e0);

    hist[tid] = 0; lcur[tid] = 0;
    __syncthreads();
    for (int i = tid; i < cnt; i += 256)
        atomicAdd(&hist[dst[e0 + i] >> BSHIFT], 1);
    __syncthreads();
    {
        const int c = hist[tid];
        lbase[tid] = c;
        __syncthreads();
        for (int off = 1; off < 256; off <<= 1) {
            int a = lbase[tid];
            int b = (tid >= off) ? lbase[tid - off] : 0;
            __syncthreads();
            lbase[tid] = a + b;
            __syncthreads();
        }
        const int inc = lbase[tid];
        lbase[tid] = inc - c;
        if (c) gbase[tid] = atomicAdd(&bcur[tid], c);
        __syncthreads();
    }
    for (int i = tid; i < cnt; i += 256) {
        const int s = src[e0 + i], d = dst[e0 + i];
        const int b = d >> BSHIFT;
        const int p = lbase[b] + atomicAdd(&lcur[b], 1);
        stage[p] = make_int2(s, d);
    }
    __syncthreads();
    for (int i = tid; i < cnt; i += 256) {
        const int2 v = stage[i];
        const int b = v.y >> BSHIFT;
        pairs[gbase[b] + (i - lbase[b])] = v;
    }
}

// K7: per-bucket CSR finalize (LDS sort, coalesced flush, node-ordered rowstart)
__global__ __launch_bounds__(256) void bucket_csr_kernel(
    const int2* __restrict__ pairs, const int* __restrict__ deg,
    const int* __restrict__ bbase, const int* __restrict__ bcnt,
    int* __restrict__ rowstart, int* __restrict__ csr_src)
{
    __shared__ int lofs[BNODES];
    __shared__ int lcur[BNODES];
    __shared__ int pscan[256];
    __shared__ int stage[CAP];     // 64KB
    const int tid = threadIdx.x;
    const int b   = blockIdx.x;
    const int nodeBase = b << BSHIFT;

    const int n0 = nodeBase + 2 * tid;
    const int d0 = (n0     < N_NODES) ? deg[n0]     : 0;
    const int d1 = (n0 + 1 < N_NODES) ? deg[n0 + 1] : 0;
    pscan[tid] = d0 + d1;
    __syncthreads();
    for (int off = 1; off < 256; off <<= 1) {
        int a = pscan[tid];
        int x = (tid >= off) ? pscan[tid - off] : 0;
        __syncthreads();
        pscan[tid] = a + x;
        __syncthreads();
    }
    const int ex = pscan[tid] - (d0 + d1);
    lofs[2 * tid]     = ex;
    lofs[2 * tid + 1] = ex + d0;
    lcur[2 * tid]     = 0;
    lcur[2 * tid + 1] = 0;

    const int base = bbase[b];
    if (n0     < N_NODES) rowstart[n0]     = base + ex;
    if (n0 + 1 < N_NODES) rowstart[n0 + 1] = base + ex + d0;
    __syncthreads();

    const int cnt = bcnt[b];
    if (cnt <= CAP) {
        for (int i = tid; i < cnt; i += 256) {
            const int2 v = pairs[base + i];
            const int ln = v.y - nodeBase;
            const int p  = lofs[ln] + atomicAdd(&lcur[ln], 1);
            stage[p] = v.x;
        }
        __syncthreads();
        for (int i = tid; i < cnt; i += 256)
            csr_src[base + i] = stage[i];
    } else {
        for (int i = tid; i < cnt; i += 256) {
            const int2 v = pairs[base + i];
            const int ln = v.y - nodeBase;
            const int p  = atomicAdd(&lcur[ln], 1);
            csr_src[base + lofs[ln] + p] = v.x;
        }
    }
}

// K8/K10: dense transform. out_bf16[node] = ((relu?)(x[node]) @ w) * norm[node].
template <bool RELU>
__global__ __launch_bounds__(256) void transform_kernel(
    const float* __restrict__ xin, const float* __restrict__ w,
    const float* __restrict__ norm, unsigned short* __restrict__ outbf)
{
    __shared__ float sw[D * D];
    const int tid = threadIdx.x;
#pragma unroll
    for (int i = 0; i < 16; ++i) sw[tid + i * 256] = w[tid + i * 256];
    __syncthreads();

    const int node = blockIdx.x * 256 + tid;
    if (node >= N_NODES) return;

    float x[D];
    const float4* p = (const float4*)(xin + (size_t)node * D);
#pragma unroll
    for (int i = 0; i < 16; ++i) {
        float4 u = p[i];
        x[i * 4 + 0] = u.x; x[i * 4 + 1] = u.y;
        x[i * 4 + 2] = u.z; x[i * 4 + 3] = u.w;
    }
    if (RELU) {
#pragma unroll
        for (int k = 0; k < D; ++k) x[k] = fmaxf(x[k], 0.f);
    }

    float acc[D];
#pragma unroll
    for (int j = 0; j < D; ++j) acc[j] = 0.f;
#pragma unroll
    for (int k = 0; k < D; ++k) {
        float a = x[k];
#pragma unroll
        for (int j = 0; j < D; ++j) acc[j] = fmaf(a, sw[k * D + j], acc[j]);
    }

    const float nn = norm[node];
    uint_t pk[32];
#pragma unroll
    for (int j = 0; j < 32; ++j)
        pk[j] = bfr(acc[2 * j] * nn) | (bfr(acc[2 * j + 1] * nn) << 16);

    uint4* po = (uint4*)(outbf + (size_t)node * D);
#pragma unroll
    for (int i = 0; i < 8; ++i)
        po[i] = make_uint4(pk[4 * i], pk[4 * i + 1], pk[4 * i + 2], pk[4 * i + 3]);
}

// K9/K11: gather aggregation over bf16 h' rows (128B each). One wave per node.
__global__ __launch_bounds__(256) void aggregate_gather(
    const unsigned short* __restrict__ hbf, const int* __restrict__ csr_src,
    const int* __restrict__ rowstart, const int* __restrict__ degv,
    const float* __restrict__ norm, float* __restrict__ out)
{
    const int node = blockIdx.x * 4 + (threadIdx.x >> 6);
    if (node >= N_NODES) return;
    const int lane = threadIdx.x & 63;
    const int grp  = lane >> 4;       // which of 4 concurrent edges
    const int lg   = lane & 15;       // 8B-chunk within the 128B row
    const uint2* hp = (const uint2*)hbf;

    const int beg = rowstart[node];
    const int end = beg + degv[node];

    float4 acc = make_float4(0.f, 0.f, 0.f, 0.f);
    for (int base = beg; base < end; base += 64) {
        int p = base + lane;
        int idx = 0;
        if (p < end) idx = csr_src[p];
        const int nb = min(64, end - base);
        const int iters = (nb + 3) >> 2;     // wave-uniform, <= 16
        for (int i = 0; i < iters; i += 8) {
            uint2 raw[8]; bool act[8];
#pragma unroll
            for (int u = 0; u < 8; ++u) {
                const int kk = (i + u) * 4 + grp;       // <= 63 always
                const int s = __shfl(idx, kk, 64);      // convergent
                act[u] = (kk < nb);
                if (act[u]) raw[u] = hp[(size_t)s * 16 + lg];
            }
#pragma unroll
            for (int u = 0; u < 8; ++u) {
                if (act[u]) {
                    acc.x += __uint_as_float(raw[u].x << 16);
                    acc.y += __uint_as_float(raw[u].x & 0xFFFF0000u);
                    acc.z += __uint_as_float(raw[u].y << 16);
                    acc.w += __uint_as_float(raw[u].y & 0xFFFF0000u);
                }
            }
        }
    }
    // fold the 4 edge-groups: lanes l, l+16, l+32, l+48 hold the same channels
#pragma unroll
    for (int off = 32; off >= 16; off >>= 1) {
        acc.x += __shfl_down(acc.x, off, 64);
        acc.y += __shfl_down(acc.y, off, 64);
        acc.z += __shfl_down(acc.z, off, 64);
        acc.w += __shfl_down(acc.w, off, 64);
    }
    if (lane < 16) {
        const float nn = norm[node];
        float4 o = make_float4(acc.x * nn, acc.y * nn, acc.z * nn, acc.w * nn);
        *(float4*)(out + (size_t)node * D + (size_t)lane * 4) = o;
    }
}

extern "C" void kernel_launch(void* const* d_in, const int* in_sizes, int n_in,
                              void* d_out, int out_size, void* d_ws, size_t ws_size,
                              hipStream_t stream)
{
    const float* emb  = (const float*)d_in[0];
    const float* gc1w = (const float*)d_in[1];
    const float* gc2w = (const float*)d_in[2];
    const float* gc1h = (const float*)d_in[3];
    const float* gc2h = (const float*)d_in[4];
    const float* w_ih = (const float*)d_in[5];
    const float* w_hh = (const float*)d_in[6];
    const float* b_ih = (const float*)d_in[7];
    const float* b_hh = (const float*)d_in[8];
    const int* src = (const int*)d_in[9];
    const int* dst = (const int*)d_in[10];

    float* ws = (float*)d_ws;
    float* gi1 = ws + OFF_GI1;
    float* gi2 = ws + OFF_GI2;
    float* gh1 = ws + OFF_GH1;
    float* gh2 = ws + OFF_GH2;
    float* w1  = ws + OFF_W1;
    float* w2  = ws + OFF_W2;
    int*   deg = (int*)(ws + OFF_DEG);
    float* nrm = ws + OFF_NORM;
    int*   rows = (int*)(ws + OFF_ROWS);
    int*   bcnt = (int*)(ws + OFF_BCNT);
    int*   bbase = (int*)(ws + OFF_BBASE);
    int*   bcur = (int*)(ws + OFF_BCUR);
    int*   csr  = (int*)(ws + OFF_CSR);
    unsigned short* hbf = (unsigned short*)(ws + OFF_H);   // bf16 h' rows
    int2*  pairs = (int2*)(ws + OFF_H + 3200000u);         // disjoint from hbf
    float* agg1 = ws + OFF_AGG1;
    float* out  = (float*)d_out;

    hipMemsetAsync(deg, 0, NPAD * sizeof(int), stream);
    hipMemsetAsync(bcnt, 0, 256 * sizeof(int), stream);

    // GRU weight evolution: x = hist, hidden = current weights
    gru_matvec<<<3072, 512, 0, stream>>>(w_ih, w_hh, gc1h, gc2h,
                                         gc1w, gc2w, gi1, gi2, gh1, gh2);
    gru_gates<<<dim3(16, 2), 256, 0, stream>>>(gi1, gh1, gi2, gh2,
                                               b_ih, b_hh, gc1w, gc2w, w1, w2);

    // degree + buckets + norm + coalesced CSR-by-dst
    deg_hist_kernel<<<512, 256, 0, stream>>>(dst, deg, bcnt);
    bucket_scan_kernel<<<1, 256, 0, stream>>>(bcnt, bbase, bcur);
    norm_kernel<<<(N_NODES + 255) / 256, 256, 0, stream>>>(deg, nrm);
    partition_kernel<<<NBUCK, 256, 0, stream>>>(src, dst, bcur, pairs);
    bucket_csr_kernel<<<NBUCK, 256, 0, stream>>>(pairs, deg, bbase, bcnt, rows, csr);

    // layer 1
    transform_kernel<false><<<(N_NODES + 255) / 256, 256, 0, stream>>>(emb, w1, nrm, hbf);
    aggregate_gather<<<(N_NODES + 3) / 4, 256, 0, stream>>>(hbf, csr, rows, deg, nrm, agg1);

    // layer 2 (relu applied to layer-1 aggregate inside the transform)
    transform_kernel<true><<<(N_NODES + 255) / 256, 256, 0, stream>>>(agg1, w2, nrm, hbf);
    aggregate_gather<<<(N_NODES + 3) / 4, 256, 0, stream>>>(hbf, csr, rows, deg, nrm, out);
}

// Round 9
// 658.355 us; speedup vs baseline: 1.2637x; 1.2637x over previous
//
#include <hip/hip_runtime.h>

typedef unsigned int uint_t;
typedef float v4f __attribute__((ext_vector_type(4)));   // native vector for nt loads

#define N_NODES 100000
#define N_EDGES 1600000
#define D 64
#define D2 4096   // D*D
#define D3 12288  // 3*D2

#define NPAD 100352u  // N_NODES rounded up

#define BSHIFT 9          // 512 nodes per bucket
#define BNODES 512
#define NBUCK 196         // ceil(100000/512)
#define CHUNK 8192        // edges per partition workgroup (196 workgroups)
#define CAP   16384       // LDS staging slots in bucket_csr (mean fill 8192)

// ---------- workspace layout (4-byte units) ----------
#define OFF_GI1   0u
#define OFF_GI2   (OFF_GI1 + D3)
#define OFF_GH1   (OFF_GI2 + D3)
#define OFF_GH2   (OFF_GH1 + D3)
#define OFF_W1    (OFF_GH2 + D3)          // 49152
#define OFF_W2    (OFF_W1 + D2)           // 53248
#define OFF_DEG   (OFF_W2 + D2)           // 57344   int[NPAD]
#define OFF_NORM  (OFF_DEG + NPAD)        // 157696  float[NPAD]
#define OFF_ROWS  (OFF_NORM + NPAD)       // 258048  int[NPAD] rowstart (node-ordered)
#define OFF_BCNT  (OFF_ROWS + NPAD)       // 358400  int[256]
#define OFF_BBASE (OFF_BCNT + 256u)       // 358656  int[256]
#define OFF_BCUR  (OFF_BBASE + 256u)      // 358912  int[256]
#define OFF_CSR   (OFF_BCUR + 256u)       // 359168  int[N_EDGES]
#define OFF_H     (OFF_CSR + 1600000u)    // 1959168 slot holds: bf16 h' (12.8MB) then int2 pairs (12.8MB)
#define OFF_AGG1  (OFF_H + 6400000u)      // 8359168 float[N*D]
// total 14,759,168 units ~= 56.3 MiB

__device__ __forceinline__ float dot4(float4 a, float4 b, float acc) {
    acc = fmaf(a.x, b.x, acc);
    acc = fmaf(a.y, b.y, acc);
    acc = fmaf(a.z, b.z, acc);
    acc = fmaf(a.w, b.w, acc);
    return acc;
}

__device__ __forceinline__ float dot4v(v4f a, float4 b, float acc) {
    acc = fmaf(a[0], b.x, acc);
    acc = fmaf(a[1], b.y, acc);
    acc = fmaf(a[2], b.z, acc);
    acc = fmaf(a[3], b.w, acc);
    return acc;
}

// round-to-nearest-even f32 -> bf16 (value range here is sane, no NaN concern)
__device__ __forceinline__ uint_t bfr(float f) {
    uint_t u = __float_as_uint(f);
    u += 0x7FFFu + ((u >> 16) & 1u);
    return u >> 16;
}

// K1: GRU matvecs. R7 post-mortem: occupancy 73% (VGPR 32) did NOT move the
// needle — 3 structures all at ~127us = 403MB/3.2TB/s. Hypothesis under test:
// the 403MB weight stream thrashes L3 every iteration (403>256MB) and the L3
// fill/hit path caps the stream. Falsifier: non-temporal weight loads (early
// evict, keep L3 for the rest of the pipeline). Structure unchanged from R7.
__global__ __launch_bounds__(512) void gru_matvec(
    const float* __restrict__ w_ih, const float* __restrict__ w_hh,
    const float* __restrict__ x1, const float* __restrict__ x2,
    const float* __restrict__ h1, const float* __restrict__ h2,
    float* __restrict__ gi1, float* __restrict__ gi2,
    float* __restrict__ gh1, float* __restrict__ gh2)
{
    __shared__ float4 sA[1024], sB[1024];   // 32 KB: the 2 x-vectors for this half
    const int tid  = threadIdx.x;
    const int half = (blockIdx.x >= 1536);
    const int blk  = blockIdx.x - (half ? 1536 : 0);

    {
        const float4* va = (const float4*)(half ? h1 : x1);
        const float4* vb = (const float4*)(half ? h2 : x2);
#pragma unroll
        for (int i = 0; i < 2; ++i) {
            const int k = tid + i * 512;
            sA[k] = va[k];
            sB[k] = vb[k];
        }
    }
    __syncthreads();

    const int wave = tid >> 6, lane = tid & 63;
    const int row  = blk * 8 + wave;                 // 0..12287
    const v4f* wr = (const v4f*)((half ? w_hh : w_ih) + (size_t)row * D2);

    float p0 = 0.f, p1 = 0.f;
#pragma unroll
    for (int g = 0; g < 4; ++g) {
        v4f a[4];
#pragma unroll
        for (int k = 0; k < 4; ++k)                  // 4 streaming nt loads in flight
            a[k] = __builtin_nontemporal_load(&wr[lane + (g * 4 + k) * 64]);
#pragma unroll
        for (int k = 0; k < 4; ++k) {
            const int idx = lane + (g * 4 + k) * 64;
            p0 = dot4v(a[k], sA[idx], p0);
            p1 = dot4v(a[k], sB[idx], p1);
        }
    }
    // full-wave shuffle reduction (convergent)
#pragma unroll
    for (int m = 32; m > 0; m >>= 1) {
        p0 += __shfl_down(p0, m, 64);
        p1 += __shfl_down(p1, m, 64);
    }
    if (lane == 0) {
        float* oA = half ? gh1 : gi1;
        float* oB = half ? gh2 : gi2;
        oA[row] = p0;
        oB[row] = p1;
    }
}

// K2: GRU gates -> evolved weights w1,w2 (fp32, 4096 each)
__global__ __launch_bounds__(256) void gru_gates(
    const float* __restrict__ gi1, const float* __restrict__ gh1,
    const float* __restrict__ gi2, const float* __restrict__ gh2,
    const float* __restrict__ b_ih, const float* __restrict__ b_hh,
    const float* __restrict__ hw1, const float* __restrict__ hw2,
    float* __restrict__ w1, float* __restrict__ w2)
{
    const int j = blockIdx.x * 256 + threadIdx.x;   // 0..4095
    const int layer = blockIdx.y;
    const float* gi = layer ? gi2 : gi1;
    const float* gh = layer ? gh2 : gh1;
    const float* hw = layer ? hw2 : hw1;
    float* wo = layer ? w2 : w1;

    float ir = gi[j]          + b_ih[j];
    float hr = gh[j]          + b_hh[j];
    float iz = gi[j + D2]     + b_ih[j + D2];
    float hz = gh[j + D2]     + b_hh[j + D2];
    float in_ = gi[j + 2*D2]  + b_ih[j + 2*D2];
    float hn = gh[j + 2*D2]   + b_hh[j + 2*D2];

    float r = 1.f / (1.f + expf(-(ir + hr)));
    float z = 1.f / (1.f + expf(-(iz + hz)));
    float n = tanhf(in_ + r * hn);
    wo[j] = (1.f - z) * n + z * hw[j];
}

// K3: fused in-degree + bucket histogram (grid-stride, LDS-pre-aggregated)
__global__ __launch_bounds__(256) void deg_hist_kernel(
    const int* __restrict__ dst, int* __restrict__ deg, int* __restrict__ bcnt)
{
    __shared__ int hist[256];
    const int tid = threadIdx.x;
    hist[tid] = 0;
    __syncthreads();
    const int stride = gridDim.x * 256;
    for (int e = blockIdx.x * 256 + tid; e < N_EDGES; e += stride) {
        const int d = dst[e];
        atomicAdd(&deg[d], 1);
        atomicAdd(&hist[d >> BSHIFT], 1);
    }
    __syncthreads();
    if (hist[tid]) atomicAdd(&bcnt[tid], hist[tid]);
}

// K4: exclusive scan of 256 bucket counts -> bucket base + write cursor
__global__ __launch_bounds__(256) void bucket_scan_kernel(
    const int* __restrict__ bcnt, int* __restrict__ bbase, int* __restrict__ bcur)
{
    __shared__ int tmp[256];
    const int tid = threadIdx.x;
    const int c = bcnt[tid];
    tmp[tid] = c;
    __syncthreads();
    for (int off = 1; off < 256; off <<= 1) {
        int a = tmp[tid];
        int b = (tid >= off) ? tmp[tid - off] : 0;
        __syncthreads();
        tmp[tid] = a + b;
        __syncthreads();
    }
    const int ex = tmp[tid] - c;
    bbase[tid] = ex;
    bcur[tid]  = ex;
}

// K5: norm = clip(deg,1)^-0.5
__global__ __launch_bounds__(256) void norm_kernel(
    const int* __restrict__ deg, float* __restrict__ norm)
{
    const int n = blockIdx.x * 256 + threadIdx.x;
    if (n < N_NODES) norm[n] = 1.0f / sqrtf(fmaxf((float)deg[n], 1.0f));
}

// K6: partition edges into dst-buckets. All global writes are coalesced runs.
__global__ __launch_bounds__(256) void partition_kernel(
    const int* __restrict__ src, const int* __restrict__ dst,
    int* __restrict__ bcur, int2* __restrict__ pairs)
{
    __shared__ int hist[256];
    __shared__ int lbase[256];
    __shared__ int gbase[256];
    __shared__ int lcur[256];
    __shared__ int2 stage[CHUNK];
    const int tid = threadIdx.x;
    const int e0  = blockIdx.x * CHUNK;
    const int cnt = min(CHUNK, N_EDGES - e0);

    hist[tid] = 0; lcur[tid] = 0;
    __syncthreads();
    for (int i = tid; i < cnt; i += 256)
        atomicAdd(&hist[dst[e0 + i] >> BSHIFT], 1);
    __syncthreads();
    {
        const int c = hist[tid];
        lbase[tid] = c;
        __syncthreads();
        for (int off = 1; off < 256; off <<= 1) {
            int a = lbase[tid];
            int b = (tid >= off) ? lbase[tid - off] : 0;
            __syncthreads();
            lbase[tid] = a + b;
            __syncthreads();
        }
        const int inc = lbase[tid];
        lbase[tid] = inc - c;
        if (c) gbase[tid] = atomicAdd(&bcur[tid], c);
        __syncthreads();
    }
    for (int i = tid; i < cnt; i += 256) {
        const int s = src[e0 + i], d = dst[e0 + i];
        const int b = d >> BSHIFT;
        const int p = lbase[b] + atomicAdd(&lcur[b], 1);
        stage[p] = make_int2(s, d);
    }
    __syncthreads();
    for (int i = tid; i < cnt; i += 256) {
        const int2 v = stage[i];
        const int b = v.y >> BSHIFT;
        pairs[gbase[b] + (i - lbase[b])] = v;
    }
}

// K7: per-bucket CSR finalize (LDS sort, coalesced flush, node-ordered rowstart)
__global__ __launch_bounds__(256) void bucket_csr_kernel(
    const int2* __restrict__ pairs, const int* __restrict__ deg,
    const int* __restrict__ bbase, const int* __restrict__ bcnt,
    int* __restrict__ rowstart, int* __restrict__ csr_src)
{
    __shared__ int lofs[BNODES];
    __shared__ int lcur[BNODES];
    __shared__ int pscan[256];
    __shared__ int stage[CAP];     // 64KB
    const int tid = threadIdx.x;
    const int b   = blockIdx.x;
    const int nodeBase = b << BSHIFT;

    const int n0 = nodeBase + 2 * tid;
    const int d0 = (n0     < N_NODES) ? deg[n0]     : 0;
    const int d1 = (n0 + 1 < N_NODES) ? deg[n0 + 1] : 0;
    pscan[tid] = d0 + d1;
    __syncthreads();
    for (int off = 1; off < 256; off <<= 1) {
        int a = pscan[tid];
        int x = (tid >= off) ? pscan[tid - off] : 0;
        __syncthreads();
        pscan[tid] = a + x;
        __syncthreads();
    }
    const int ex = pscan[tid] - (d0 + d1);
    lofs[2 * tid]     = ex;
    lofs[2 * tid + 1] = ex + d0;
    lcur[2 * tid]     = 0;
    lcur[2 * tid + 1] = 0;

    const int base = bbase[b];
    if (n0     < N_NODES) rowstart[n0]     = base + ex;
    if (n0 + 1 < N_NODES) rowstart[n0 + 1] = base + ex + d0;
    __syncthreads();

    const int cnt = bcnt[b];
    if (cnt <= CAP) {
        for (int i = tid; i < cnt; i += 256) {
            const int2 v = pairs[base + i];
            const int ln = v.y - nodeBase;
            const int p  = lofs[ln] + atomicAdd(&lcur[ln], 1);
            stage[p] = v.x;
        }
        __syncthreads();
        for (int i = tid; i < cnt; i += 256)
            csr_src[base + i] = stage[i];
    } else {
        for (int i = tid; i < cnt; i += 256) {
            const int2 v = pairs[base + i];
            const int ln = v.y - nodeBase;
            const int p  = atomicAdd(&lcur[ln], 1);
            csr_src[base + lofs[ln] + p] = v.x;
        }
    }
}

// K8/K10: dense transform. out_bf16[node] = ((relu?)(x[node]) @ w) * norm[node].
template <bool RELU>
__global__ __launch_bounds__(256) void transform_kernel(
    const float* __restrict__ xin, const float* __restrict__ w,
    const float* __restrict__ norm, unsigned short* __restrict__ outbf)
{
    __shared__ float sw[D * D];
    const int tid = threadIdx.x;
#pragma unroll
    for (int i = 0; i < 16; ++i) sw[tid + i * 256] = w[tid + i * 256];
    __syncthreads();

    const int node = blockIdx.x * 256 + tid;
    if (node >= N_NODES) return;

    float x[D];
    const float4* p = (const float4*)(xin + (size_t)node * D);
#pragma unroll
    for (int i = 0; i < 16; ++i) {
        float4 u = p[i];
        x[i * 4 + 0] = u.x; x[i * 4 + 1] = u.y;
        x[i * 4 + 2] = u.z; x[i * 4 + 3] = u.w;
    }
    if (RELU) {
#pragma unroll
        for (int k = 0; k < D; ++k) x[k] = fmaxf(x[k], 0.f);
    }

    float acc[D];
#pragma unroll
    for (int j = 0; j < D; ++j) acc[j] = 0.f;
#pragma unroll
    for (int k = 0; k < D; ++k) {
        float a = x[k];
#pragma unroll
        for (int j = 0; j < D; ++j) acc[j] = fmaf(a, sw[k * D + j], acc[j]);
    }

    const float nn = norm[node];
    uint_t pk[32];
#pragma unroll
    for (int j = 0; j < 32; ++j)
        pk[j] = bfr(acc[2 * j] * nn) | (bfr(acc[2 * j + 1] * nn) << 16);

    uint4* po = (uint4*)(outbf + (size_t)node * D);
#pragma unroll
    for (int i = 0; i < 8; ++i)
        po[i] = make_uint4(pk[4 * i], pk[4 * i + 1], pk[4 * i + 2], pk[4 * i + 3]);
}

// K9/K11: gather aggregation over bf16 h' rows (128B each).
// R8 rewrite: ONE 16-LANE GROUP PER NODE (4 nodes/wave, 16/block).
//  - csr_src[beg+k] is a same-address broadcast load within the group (1 req)
//  - each lane owns 4 output channels (uint2 = 8B of the 128B row)
//  - NO cross-lane ops anywhere -> group divergence is safe
//  - 8-deep unrolled independent load chains for MLP
//  - output: 16 lanes x 16B = 256B/node, 4 consecutive nodes/wave -> 1KB coalesced
__global__ __launch_bounds__(256) void aggregate_gather(
    const unsigned short* __restrict__ hbf, const int* __restrict__ csr_src,
    const int* __restrict__ rowstart, const int* __restrict__ degv,
    const float* __restrict__ norm, float* __restrict__ out)
{
    const int tid  = threadIdx.x;
    const int node = blockIdx.x * 16 + (tid >> 4);
    if (node >= N_NODES) return;
    const int lg = tid & 15;
    const uint2* hp = (const uint2*)hbf;

    const int beg = rowstart[node];
    const int dg  = degv[node];

    float4 acc = make_float4(0.f, 0.f, 0.f, 0.f);
    int k = 0;
    for (; k + 8 <= dg; k += 8) {
        int s[8];
#pragma unroll
        for (int u = 0; u < 8; ++u) s[u] = csr_src[beg + k + u];
        uint2 r[8];
#pragma unroll
        for (int u = 0; u < 8; ++u) r[u] = hp[(size_t)s[u] * 16 + lg];
#pragma unroll
        for (int u = 0; u < 8; ++u) {
            acc.x += __uint_as_float(r[u].x << 16);
            acc.y += __uint_as_float(r[u].x & 0xFFFF0000u);
            acc.z += __uint_as_float(r[u].y << 16);
            acc.w += __uint_as_float(r[u].y & 0xFFFF0000u);
        }
    }
    for (; k < dg; ++k) {
        const int s = csr_src[beg + k];
        const uint2 r = hp[(size_t)s * 16 + lg];
        acc.x += __uint_as_float(r.x << 16);
        acc.y += __uint_as_float(r.x & 0xFFFF0000u);
        acc.z += __uint_as_float(r.y << 16);
        acc.w += __uint_as_float(r.y & 0xFFFF0000u);
    }

    const float nn = norm[node];
    float4 o = make_float4(acc.x * nn, acc.y * nn, acc.z * nn, acc.w * nn);
    *(float4*)(out + (size_t)node * D + (size_t)lg * 4) = o;
}

extern "C" void kernel_launch(void* const* d_in, const int* in_sizes, int n_in,
                              void* d_out, int out_size, void* d_ws, size_t ws_size,
                              hipStream_t stream)
{
    const float* emb  = (const float*)d_in[0];
    const float* gc1w = (const float*)d_in[1];
    const float* gc2w = (const float*)d_in[2];
    const float* gc1h = (const float*)d_in[3];
    const float* gc2h = (const float*)d_in[4];
    const float* w_ih = (const float*)d_in[5];
    const float* w_hh = (const float*)d_in[6];
    const float* b_ih = (const float*)d_in[7];
    const float* b_hh = (const float*)d_in[8];
    const int* src = (const int*)d_in[9];
    const int* dst = (const int*)d_in[10];

    float* ws = (float*)d_ws;
    float* gi1 = ws + OFF_GI1;
    float* gi2 = ws + OFF_GI2;
    float* gh1 = ws + OFF_GH1;
    float* gh2 = ws + OFF_GH2;
    float* w1  = ws + OFF_W1;
    float* w2  = ws + OFF_W2;
    int*   deg = (int*)(ws + OFF_DEG);
    float* nrm = ws + OFF_NORM;
    int*   rows = (int*)(ws + OFF_ROWS);
    int*   bcnt = (int*)(ws + OFF_BCNT);
    int*   bbase = (int*)(ws + OFF_BBASE);
    int*   bcur = (int*)(ws + OFF_BCUR);
    int*   csr  = (int*)(ws + OFF_CSR);
    unsigned short* hbf = (unsigned short*)(ws + OFF_H);   // bf16 h' rows
    int2*  pairs = (int2*)(ws + OFF_H + 3200000u);         // disjoint from hbf
    float* agg1 = ws + OFF_AGG1;
    float* out  = (float*)d_out;

    hipMemsetAsync(deg, 0, NPAD * sizeof(int), stream);
    hipMemsetAsync(bcnt, 0, 256 * sizeof(int), stream);

    // GRU weight evolution: x = hist, hidden = current weights
    gru_matvec<<<3072, 512, 0, stream>>>(w_ih, w_hh, gc1h, gc2h,
                                         gc1w, gc2w, gi1, gi2, gh1, gh2);
    gru_gates<<<dim3(16, 2), 256, 0, stream>>>(gi1, gh1, gi2, gh2,
                                               b_ih, b_hh, gc1w, gc2w, w1, w2);

    // degree + buckets + norm + coalesced CSR-by-dst
    deg_hist_kernel<<<512, 256, 0, stream>>>(dst, deg, bcnt);
    bucket_scan_kernel<<<1, 256, 0, stream>>>(bcnt, bbase, bcur);
    norm_kernel<<<(N_NODES + 255) / 256, 256, 0, stream>>>(deg, nrm);
    partition_kernel<<<NBUCK, 256, 0, stream>>>(src, dst, bcur, pairs);
    bucket_csr_kernel<<<NBUCK, 256, 0, stream>>>(pairs, deg, bbase, bcnt, rows, csr);

    // layer 1
    transform_kernel<false><<<(N_NODES + 255) / 256, 256, 0, stream>>>(emb, w1, nrm, hbf);
    aggregate_gather<<<(N_NODES + 15) / 16, 256, 0, stream>>>(hbf, csr, rows, deg, nrm, agg1);

    // layer 2 (relu applied to layer-1 aggregate inside the transform)
    transform_kernel<true><<<(N_NODES + 255) / 256, 256, 0, stream>>>(agg1, w2, nrm, hbf);
    aggregate_gather<<<(N_NODES + 15) / 16, 256, 0, stream>>>(hbf, csr, rows, deg, nrm, out);
}

// Round 10
// 608.839 us; speedup vs baseline: 1.3665x; 1.0813x over previous
//
#include <hip/hip_runtime.h>

typedef unsigned int uint_t;
typedef float v4f __attribute__((ext_vector_type(4)));   // native vector for nt loads

#define N_NODES 100000
#define N_EDGES 1600000
#define D 64
#define D2 4096   // D*D
#define D3 12288  // 3*D2

#define NPAD 100352u  // N_NODES rounded up

#define BSHIFT 9          // 512 nodes per bucket
#define BNODES 512
#define NBUCK 196         // ceil(100000/512)
#define CHUNK 8192        // edges per partition block (196 edge blocks)
#define CAP   16384       // fixed stride per bucket (mean fill 8163, ~90 sigma)
#define GRUBLK 3072       // gru blocks in mega1

// ---------- workspace layout (4-byte units) ----------
#define OFF_GI1   0u
#define OFF_GI2   (OFF_GI1 + D3)
#define OFF_GH1   (OFF_GI2 + D3)
#define OFF_GH2   (OFF_GH1 + D3)
#define OFF_W1    (OFF_GH2 + D3)            // 49152
#define OFF_W2    (OFF_W1 + D2)             // 53248
#define OFF_DEG   (OFF_W2 + D2)             // 57344   int[NPAD]
#define OFF_BCUR  (OFF_DEG + NPAD)          // 157696  int[256] (zeroed with deg)
#define OFF_NORM  (OFF_BCUR + 256u)         // 157952  float[NPAD]
#define OFF_ROWS  (OFF_NORM + NPAD)         // 258304  int[NPAD] rowstart (node-ordered)
#define OFF_CSR   (OFF_ROWS + NPAD)         // 358656  int[N_EDGES]
#define OFF_H     (OFF_CSR + 1600000u)      // 1958656 bf16 h' rows (3.2M units)
#define OFF_AGG1  (OFF_H + 3200000u)        // 5158656 float[N*D]
#define OFF_PAIRS (OFF_AGG1 + 6400000u)     // 11558656 int2[196*CAP] (25.7MB)
// total ~18.0M units ~= 68.6 MiB

__device__ __forceinline__ float dot4v(v4f a, float4 b, float acc) {
    acc = fmaf(a[0], b.x, acc);
    acc = fmaf(a[1], b.y, acc);
    acc = fmaf(a[2], b.z, acc);
    acc = fmaf(a[3], b.w, acc);
    return acc;
}

// round-to-nearest-even f32 -> bf16
__device__ __forceinline__ uint_t bfr(float f) {
    uint_t u = __float_as_uint(f);
    u += 0x7FFFu + ((u >> 16) & 1u);
    return u >> 16;
}

// ---- MEGA1: gru matvec (memory-latency-bound) OVERLAPPED with the fused
// edge pass (deg count + bucket partition). Edge blocks are FIRST in the grid
// so they dispatch early and hide under gru's ~115us stream.
// Edge path: per-chunk LDS hist -> scan -> LDS bucket-sort -> per-bucket
// atomic reservation in FIXED-STRIDE region pairs[b*CAP + r] (no global scan
// dependency). Final bcur[b] == bucket count, consumed by bucket_csr.
struct PartLds {
    int hist[256];
    int lbase[256];
    int gbase[256];
    int lcur[256];
    int2 stage[CHUNK];     // 64KB
};
struct GruLds {
    float4 sA[1024];       // 16KB
    float4 sB[1024];       // 16KB
};

__global__ __launch_bounds__(512) void mega1(
    const float* __restrict__ w_ih, const float* __restrict__ w_hh,
    const float* __restrict__ x1, const float* __restrict__ x2,
    const float* __restrict__ h1, const float* __restrict__ h2,
    float* __restrict__ gi1, float* __restrict__ gi2,
    float* __restrict__ gh1, float* __restrict__ gh2,
    const int* __restrict__ src, const int* __restrict__ dst,
    int* __restrict__ deg, int* __restrict__ bcur, int2* __restrict__ pairs)
{
    __shared__ __align__(16) char ldsraw[sizeof(PartLds)];   // 68KB union
    const int tid = threadIdx.x;

    if (blockIdx.x < NBUCK) {
        // ---------------- edge partition chunk ----------------
        PartLds& P = *reinterpret_cast<PartLds*>(ldsraw);
        const int e0  = blockIdx.x * CHUNK;
        const int cnt = min(CHUNK, N_EDGES - e0);

        if (tid < 256) { P.hist[tid] = 0; P.lcur[tid] = 0; }
        __syncthreads();
        for (int i = tid; i < cnt; i += 512) {
            const int d = dst[e0 + i];
            atomicAdd(&deg[d], 1);
            atomicAdd(&P.hist[d >> BSHIFT], 1);
        }
        __syncthreads();
        if (tid < 256) P.lbase[tid] = P.hist[tid];
        __syncthreads();
        for (int off = 1; off < 256; off <<= 1) {
            int a = 0, b = 0;
            if (tid < 256) { a = P.lbase[tid]; b = (tid >= off) ? P.lbase[tid - off] : 0; }
            __syncthreads();
            if (tid < 256) P.lbase[tid] = a + b;
            __syncthreads();
        }
        if (tid < 256) {
            const int c = P.hist[tid];
            P.lbase[tid] -= c;                               // exclusive
            P.gbase[tid] = c ? atomicAdd(&bcur[tid], c) : 0; // bucket-local reserve
        }
        __syncthreads();
        for (int i = tid; i < cnt; i += 512) {
            const int s = src[e0 + i], d = dst[e0 + i];
            const int b = d >> BSHIFT;
            const int p = P.lbase[b] + atomicAdd(&P.lcur[b], 1);
            P.stage[p] = make_int2(s, d);
        }
        __syncthreads();
        // flush: coalesced runs per bucket into its fixed-stride region
        for (int i = tid; i < cnt; i += 512) {
            const int2 v = P.stage[i];
            const int b = v.y >> BSHIFT;
            const int gp = P.gbase[b] + (i - P.lbase[b]);
            if (gp < CAP) pairs[(size_t)b * CAP + gp] = v;
        }
    } else {
        // ---------------- gru matvec (R9 structure, nt loads) ----------------
        GruLds& G = *reinterpret_cast<GruLds*>(ldsraw);
        const int gb   = blockIdx.x - NBUCK;       // 0..3071
        const int half = (gb >= GRUBLK / 2);
        const int blk  = gb - (half ? GRUBLK / 2 : 0);

        {
            const float4* va = (const float4*)(half ? h1 : x1);
            const float4* vb = (const float4*)(half ? h2 : x2);
#pragma unroll
            for (int i = 0; i < 2; ++i) {
                const int k = tid + i * 512;
                G.sA[k] = va[k];
                G.sB[k] = vb[k];
            }
        }
        __syncthreads();

        const int wave = tid >> 6, lane = tid & 63;
        const int row  = blk * 8 + wave;           // 0..12287
        const v4f* wr = (const v4f*)((half ? w_hh : w_ih) + (size_t)row * D2);

        float p0 = 0.f, p1 = 0.f;
#pragma unroll
        for (int g = 0; g < 4; ++g) {
            v4f a[4];
#pragma unroll
            for (int k = 0; k < 4; ++k)
                a[k] = __builtin_nontemporal_load(&wr[lane + (g * 4 + k) * 64]);
#pragma unroll
            for (int k = 0; k < 4; ++k) {
                const int idx = lane + (g * 4 + k) * 64;
                p0 = dot4v(a[k], G.sA[idx], p0);
                p1 = dot4v(a[k], G.sB[idx], p1);
            }
        }
#pragma unroll
        for (int m = 32; m > 0; m >>= 1) {
            p0 += __shfl_down(p0, m, 64);
            p1 += __shfl_down(p1, m, 64);
        }
        if (lane == 0) {
            float* oA = half ? gh1 : gi1;
            float* oB = half ? gh2 : gi2;
            oA[row] = p0;
            oB[row] = p1;
        }
    }
}

// K2: GRU gates (blocks 0..31) + norm (blocks 32..422), fused.
__global__ __launch_bounds__(256) void gates_norm_kernel(
    const float* __restrict__ gi1, const float* __restrict__ gh1,
    const float* __restrict__ gi2, const float* __restrict__ gh2,
    const float* __restrict__ b_ih, const float* __restrict__ b_hh,
    const float* __restrict__ hw1, const float* __restrict__ hw2,
    float* __restrict__ w1, float* __restrict__ w2,
    const int* __restrict__ deg, float* __restrict__ norm)
{
    const int blk = blockIdx.x;
    const int tid = threadIdx.x;
    if (blk < 32) {
        const int layer = blk >> 4;
        const int j = (blk & 15) * 256 + tid;     // 0..4095
        const float* gi = layer ? gi2 : gi1;
        const float* gh = layer ? gh2 : gh1;
        const float* hw = layer ? hw2 : hw1;
        float* wo = layer ? w2 : w1;

        float ir = gi[j]          + b_ih[j];
        float hr = gh[j]          + b_hh[j];
        float iz = gi[j + D2]     + b_ih[j + D2];
        float hz = gh[j + D2]     + b_hh[j + D2];
        float in_ = gi[j + 2*D2]  + b_ih[j + 2*D2];
        float hn = gh[j + 2*D2]   + b_hh[j + 2*D2];

        float r = 1.f / (1.f + expf(-(ir + hr)));
        float z = 1.f / (1.f + expf(-(iz + hz)));
        float n = tanhf(in_ + r * hn);
        wo[j] = (1.f - z) * n + z * hw[j];
    } else {
        const int n = (blk - 32) * 256 + tid;
        if (n < N_NODES) norm[n] = 1.0f / sqrtf(fmaxf((float)deg[n], 1.0f));
    }
}

// K3: per-bucket CSR finalize. Computes its own global base by scanning the
// 196 final bcur counts in-block (replaces bucket_scan_kernel). LDS sort of
// the bucket's edges, coalesced flush, node-ordered rowstart.
__global__ __launch_bounds__(256) void bucket_csr_kernel(
    const int2* __restrict__ pairs, const int* __restrict__ deg,
    const int* __restrict__ bcnt,            // final bcur
    int* __restrict__ rowstart, int* __restrict__ csr_src)
{
    __shared__ int lofs[BNODES];
    __shared__ int lcur[BNODES];
    __shared__ int pscan[256];
    __shared__ int bscan[256];
    __shared__ int stage[CAP];     // 64KB
    const int tid = threadIdx.x;
    const int b   = blockIdx.x;
    const int nodeBase = b << BSHIFT;

    // exclusive scan of bucket counts -> base of bucket b in the final CSR
    const int cb = (tid < NBUCK) ? bcnt[tid] : 0;
    bscan[tid] = cb;
    __syncthreads();
    for (int off = 1; off < 256; off <<= 1) {
        int a = bscan[tid];
        int x = (tid >= off) ? bscan[tid - off] : 0;
        __syncthreads();
        bscan[tid] = a + x;
        __syncthreads();
    }
    const int cnt  = bcnt[b];
    const int base = bscan[b] - cnt;

    // scan 512 local degrees (2 per thread) -> node-ordered offsets
    const int n0 = nodeBase + 2 * tid;
    const int d0 = (n0     < N_NODES) ? deg[n0]     : 0;
    const int d1 = (n0 + 1 < N_NODES) ? deg[n0 + 1] : 0;
    pscan[tid] = d0 + d1;
    __syncthreads();
    for (int off = 1; off < 256; off <<= 1) {
        int a = pscan[tid];
        int x = (tid >= off) ? pscan[tid - off] : 0;
        __syncthreads();
        pscan[tid] = a + x;
        __syncthreads();
    }
    const int ex = pscan[tid] - (d0 + d1);
    lofs[2 * tid]     = ex;
    lofs[2 * tid + 1] = ex + d0;
    lcur[2 * tid]     = 0;
    lcur[2 * tid + 1] = 0;

    if (n0     < N_NODES) rowstart[n0]     = base + ex;
    if (n0 + 1 < N_NODES) rowstart[n0 + 1] = base + ex + d0;
    __syncthreads();

    const int2* bp = pairs + (size_t)b * CAP;
    for (int i = tid; i < cnt; i += 256) {
        const int2 v = bp[i];
        const int ln = v.y - nodeBase;
        const int p  = lofs[ln] + atomicAdd(&lcur[ln], 1);
        stage[p] = v.x;
    }
    __syncthreads();
    for (int i = tid; i < cnt; i += 256)
        csr_src[base + i] = stage[i];
}

// K4/K6: dense transform. out_bf16[node] = ((relu?)(x[node]) @ w) * norm[node].
template <bool RELU>
__global__ __launch_bounds__(256) void transform_kernel(
    const float* __restrict__ xin, const float* __restrict__ w,
    const float* __restrict__ norm, unsigned short* __restrict__ outbf)
{
    __shared__ float sw[D * D];
    const int tid = threadIdx.x;
#pragma unroll
    for (int i = 0; i < 16; ++i) sw[tid + i * 256] = w[tid + i * 256];
    __syncthreads();

    const int node = blockIdx.x * 256 + tid;
    if (node >= N_NODES) return;

    float x[D];
    const float4* p = (const float4*)(xin + (size_t)node * D);
#pragma unroll
    for (int i = 0; i < 16; ++i) {
        float4 u = p[i];
        x[i * 4 + 0] = u.x; x[i * 4 + 1] = u.y;
        x[i * 4 + 2] = u.z; x[i * 4 + 3] = u.w;
    }
    if (RELU) {
#pragma unroll
        for (int k = 0; k < D; ++k) x[k] = fmaxf(x[k], 0.f);
    }

    float acc[D];
#pragma unroll
    for (int j = 0; j < D; ++j) acc[j] = 0.f;
#pragma unroll
    for (int k = 0; k < D; ++k) {
        float a = x[k];
#pragma unroll
        for (int j = 0; j < D; ++j) acc[j] = fmaf(a, sw[k * D + j], acc[j]);
    }

    const float nn = norm[node];
    uint_t pk[32];
#pragma unroll
    for (int j = 0; j < 32; ++j)
        pk[j] = bfr(acc[2 * j] * nn) | (bfr(acc[2 * j + 1] * nn) << 16);

    uint4* po = (uint4*)(outbf + (size_t)node * D);
#pragma unroll
    for (int i = 0; i < 8; ++i)
        po[i] = make_uint4(pk[4 * i], pk[4 * i + 1], pk[4 * i + 2], pk[4 * i + 3]);
}

// K5/K7: gather aggregation over bf16 h' rows. One 16-lane group per node.
__global__ __launch_bounds__(256) void aggregate_gather(
    const unsigned short* __restrict__ hbf, const int* __restrict__ csr_src,
    const int* __restrict__ rowstart, const int* __restrict__ degv,
    const float* __restrict__ norm, float* __restrict__ out)
{
    const int tid  = threadIdx.x;
    const int node = blockIdx.x * 16 + (tid >> 4);
    if (node >= N_NODES) return;
    const int lg = tid & 15;
    const uint2* hp = (const uint2*)hbf;

    const int beg = rowstart[node];
    const int dg  = degv[node];

    float4 acc = make_float4(0.f, 0.f, 0.f, 0.f);
    int k = 0;
    for (; k + 8 <= dg; k += 8) {
        int s[8];
#pragma unroll
        for (int u = 0; u < 8; ++u) s[u] = csr_src[beg + k + u];
        uint2 r[8];
#pragma unroll
        for (int u = 0; u < 8; ++u) r[u] = hp[(size_t)s[u] * 16 + lg];
#pragma unroll
        for (int u = 0; u < 8; ++u) {
            acc.x += __uint_as_float(r[u].x << 16);
            acc.y += __uint_as_float(r[u].x & 0xFFFF0000u);
            acc.z += __uint_as_float(r[u].y << 16);
            acc.w += __uint_as_float(r[u].y & 0xFFFF0000u);
        }
    }
    for (; k < dg; ++k) {
        const int s = csr_src[beg + k];
        const uint2 r = hp[(size_t)s * 16 + lg];
        acc.x += __uint_as_float(r.x << 16);
        acc.y += __uint_as_float(r.x & 0xFFFF0000u);
        acc.z += __uint_as_float(r.y << 16);
        acc.w += __uint_as_float(r.y & 0xFFFF0000u);
    }

    const float nn = norm[node];
    float4 o = make_float4(acc.x * nn, acc.y * nn, acc.z * nn, acc.w * nn);
    *(float4*)(out + (size_t)node * D + (size_t)lg * 4) = o;
}

extern "C" void kernel_launch(void* const* d_in, const int* in_sizes, int n_in,
                              void* d_out, int out_size, void* d_ws, size_t ws_size,
                              hipStream_t stream)
{
    const float* emb  = (const float*)d_in[0];
    const float* gc1w = (const float*)d_in[1];
    const float* gc2w = (const float*)d_in[2];
    const float* gc1h = (const float*)d_in[3];
    const float* gc2h = (const float*)d_in[4];
    const float* w_ih = (const float*)d_in[5];
    const float* w_hh = (const float*)d_in[6];
    const float* b_ih = (const float*)d_in[7];
    const float* b_hh = (const float*)d_in[8];
    const int* src = (const int*)d_in[9];
    const int* dst = (const int*)d_in[10];

    float* ws = (float*)d_ws;
    float* gi1 = ws + OFF_GI1;
    float* gi2 = ws + OFF_GI2;
    float* gh1 = ws + OFF_GH1;
    float* gh2 = ws + OFF_GH2;
    float* w1  = ws + OFF_W1;
    float* w2  = ws + OFF_W2;
    int*   deg = (int*)(ws + OFF_DEG);
    int*   bcur = (int*)(ws + OFF_BCUR);
    float* nrm = ws + OFF_NORM;
    int*   rows = (int*)(ws + OFF_ROWS);
    int*   csr  = (int*)(ws + OFF_CSR);
    unsigned short* hbf = (unsigned short*)(ws + OFF_H);
    float* agg1 = ws + OFF_AGG1;
    int2*  pairs = (int2*)(ws + OFF_PAIRS);
    float* out  = (float*)d_out;

    // deg[NPAD] and bcur[256] are contiguous: one memset
    hipMemsetAsync(deg, 0, (NPAD + 256) * sizeof(int), stream);

    // gru matvec OVERLAPPED with edge deg+partition
    mega1<<<NBUCK + GRUBLK, 512, 0, stream>>>(
        w_ih, w_hh, gc1h, gc2h, gc1w, gc2w, gi1, gi2, gh1, gh2,
        src, dst, deg, bcur, pairs);

    // gates + norm (fused, independent halves)
    gates_norm_kernel<<<32 + (N_NODES + 255) / 256, 256, 0, stream>>>(
        gi1, gh1, gi2, gh2, b_ih, b_hh, gc1w, gc2w, w1, w2, deg, nrm);

    // CSR finalize (self-scanning base)
    bucket_csr_kernel<<<NBUCK, 256, 0, stream>>>(pairs, deg, bcur, rows, csr);

    // layer 1
    transform_kernel<false><<<(N_NODES + 255) / 256, 256, 0, stream>>>(emb, w1, nrm, hbf);
    aggregate_gather<<<(N_NODES + 15) / 16, 256, 0, stream>>>(hbf, csr, rows, deg, nrm, agg1);

    // layer 2
    transform_kernel<true><<<(N_NODES + 255) / 256, 256, 0, stream>>>(agg1, w2, nrm, hbf);
    aggregate_gather<<<(N_NODES + 15) / 16, 256, 0, stream>>>(hbf, csr, rows, deg, nrm, out);
}